// Round 1
// baseline (424.354 us; speedup 1.0000x reference)
//
#include <hip/hip_runtime.h>

// Local variance over a 5x5 sliding window, reflect padding (jnp.pad mode="reflect":
// mirror WITHOUT repeating the edge: idx -1 -> 1, idx H -> H-2).
// Separable box filter through LDS: vertical sums of x and x^2, then horizontal.
//
// Tile: 64 (W) x 32 (H) outputs per block, 256 threads.
// Input stage region: (64+4) x (32+4) = 68 x 36 floats.

constexpr int PS = 5;          // patch size (fixed by the problem instance)
constexpr int PAD = PS / 2;    // 2
constexpr int TW = 64;         // output tile width
constexpr int TH = 32;         // output tile height
constexpr int IW = TW + 2 * PAD;  // 68
constexpr int IH = TH + 2 * PAD;  // 36
constexpr int NTHREADS = 256;

__global__ __launch_bounds__(NTHREADS)
void lvar5x5_kernel(const float* __restrict__ in, float* __restrict__ out,
                    int H, int W) {
    __shared__ float sx[IH][IW];        // staged input (with halo)
    __shared__ float cs[TH][IW];        // vertical sums of x
    __shared__ float cs2[TH][IW];       // vertical sums of x^2

    const int bx = blockIdx.x;          // tile col
    const int by = blockIdx.y;          // tile row
    const int bc = blockIdx.z;          // fused batch*channel
    const float* img = in + (size_t)bc * H * W;
    float* o = out + (size_t)bc * H * W;

    const int x0 = bx * TW - PAD;       // input-region origin (may be negative)
    const int y0 = by * TH - PAD;

    // ---- Stage 1: global -> LDS with reflect indexing -------------------
    for (int idx = threadIdx.x; idx < IH * IW; idx += NTHREADS) {
        const int r = idx / IW;
        const int c = idx - r * IW;
        int gy = y0 + r;
        int gx = x0 + c;
        gy = (gy < 0) ? -gy : ((gy >= H) ? (2 * H - 2 - gy) : gy);
        gx = (gx < 0) ? -gx : ((gx >= W) ? (2 * W - 2 - gx) : gx);
        sx[r][c] = img[(size_t)gy * W + gx];
    }
    __syncthreads();

    // ---- Stage 2: vertical 5-tap sums of x and x^2 ----------------------
    for (int idx = threadIdx.x; idx < TH * IW; idx += NTHREADS) {
        const int r = idx / IW;
        const int c = idx - r * IW;
        float s = 0.0f, s2 = 0.0f;
#pragma unroll
        for (int k = 0; k < PS; ++k) {
            const float v = sx[r + k][c];
            s += v;
            s2 = fmaf(v, v, s2);
        }
        cs[r][c] = s;
        cs2[r][c] = s2;
    }
    __syncthreads();

    // ---- Stage 3: horizontal 5-tap sums -> variance -> global -----------
    const float inv_n = 1.0f / (float)(PS * PS);
    for (int idx = threadIdx.x; idx < TH * TW; idx += NTHREADS) {
        const int r = idx >> 6;          // / TW (TW == 64)
        const int c = idx & (TW - 1);    // % TW
        float s = 0.0f, s2 = 0.0f;
#pragma unroll
        for (int k = 0; k < PS; ++k) {
            s += cs[r][c + k];
            s2 += cs2[r][c + k];
        }
        const float m = s * inv_n;
        const float var = fmaf(-m, m, s2 * inv_n);
        o[(size_t)(by * TH + r) * W + (bx * TW + c)] = var;
    }
}

extern "C" void kernel_launch(void* const* d_in, const int* in_sizes, int n_in,
                              void* d_out, int out_size, void* d_ws, size_t ws_size,
                              hipStream_t stream) {
    const float* image = (const float*)d_in[0];
    float* out = (float*)d_out;

    // Shape fixed by the reference setup: (16, 3, 1024, 1024) fp32, patch_size=5.
    const int H = 1024, W = 1024;
    const int BC = out_size / (H * W);   // 48

    dim3 grid(W / TW, H / TH, BC);       // (16, 32, 48)
    dim3 block(NTHREADS);
    lvar5x5_kernel<<<grid, block, 0, stream>>>(image, out, H, W);
}

// Round 2
// 406.161 us; speedup vs baseline: 1.0448x; 1.0448x over previous
//
#include <hip/hip_runtime.h>

// Local variance over a 5x5 sliding window, reflect padding.
// Separable box filter through LDS, fully float4-vectorized:
//   stage1: global -> LDS (float4 fast path for interior blocks)
//   stage2: vertical 5-tap sums of x and x^2 (b128 LDS reads/writes)
//   stage3: horizontal 5-tap sliding sums, 4 outputs/thread, float4 store
//
// Tile: 64 (W) x 32 (H) outputs per block, 256 threads.
// Staged region: 72 (4-aligned origin bx*64-4) x 36 floats.

constexpr int PS  = 5;
constexpr int PAD = 2;
constexpr int TW  = 64;          // output tile width
constexpr int TH  = 32;          // output tile height
constexpr int IWP = 72;          // staged width (4-aligned halo)
constexpr int IH  = TH + 2 * PAD;   // 36
constexpr int NT  = 256;

__global__ __launch_bounds__(NT)
void lvar5x5_kernel(const float* __restrict__ in, float* __restrict__ out,
                    int H, int W) {
    __shared__ float sx [IH][IWP];   // staged input (halo)
    __shared__ float cs [TH][IWP];   // vertical sums of x
    __shared__ float cs2[TH][IWP];   // vertical sums of x^2

    const int bx = blockIdx.x;
    const int by = blockIdx.y;
    const int bc = blockIdx.z;
    const float* img = in  + (size_t)bc * H * W;
    float*       o   = out + (size_t)bc * H * W;

    const int x0 = bx * TW - 4;      // 4-aligned staged origin (halo+slack)
    const int y0 = by * TH - PAD;

    // ---- Stage 1: global -> LDS ----------------------------------------
    const bool interior = (x0 >= 0) && (x0 + IWP <= W) &&
                          (y0 >= 0) && (y0 + IH  <= H);
    if (interior) {
        // 36 rows x 18 float4 = 648 vector loads per block
        for (int f = threadIdx.x; f < IH * (IWP / 4); f += NT) {
            const int r  = f / (IWP / 4);
            const int c4 = f - r * (IWP / 4);
            const float4 v = *reinterpret_cast<const float4*>(
                img + (size_t)(y0 + r) * W + x0 + c4 * 4);
            *reinterpret_cast<float4*>(&sx[r][c4 * 4]) = v;
        }
    } else {
        // border blocks: scalar with reflect indexing (no edge repeat)
        for (int idx = threadIdx.x; idx < IH * IWP; idx += NT) {
            const int r = idx / IWP;
            const int c = idx - r * IWP;
            int gy = y0 + r;
            int gx = x0 + c;
            gy = (gy < 0) ? -gy : ((gy >= H) ? (2 * H - 2 - gy) : gy);
            gx = (gx < 0) ? -gx : ((gx >= W) ? (2 * W - 2 - gx) : gx);
            sx[r][c] = img[(size_t)gy * W + gx];
        }
    }
    __syncthreads();

    // ---- Stage 2: vertical 5-tap sums, 4 columns per task ---------------
    for (int t = threadIdx.x; t < TH * (IWP / 4); t += NT) {
        const int r = t / (IWP / 4);
        const int g = t - r * (IWP / 4);
        const int j = g * 4;
        float4 s  = make_float4(0.f, 0.f, 0.f, 0.f);
        float4 s2 = make_float4(0.f, 0.f, 0.f, 0.f);
#pragma unroll
        for (int k = 0; k < PS; ++k) {
            const float4 v = *reinterpret_cast<const float4*>(&sx[r + k][j]);
            s.x += v.x; s.y += v.y; s.z += v.z; s.w += v.w;
            s2.x = fmaf(v.x, v.x, s2.x);
            s2.y = fmaf(v.y, v.y, s2.y);
            s2.z = fmaf(v.z, v.z, s2.z);
            s2.w = fmaf(v.w, v.w, s2.w);
        }
        *reinterpret_cast<float4*>(&cs [r][j]) = s;
        *reinterpret_cast<float4*>(&cs2[r][j]) = s2;
    }
    __syncthreads();

    // ---- Stage 3: horizontal sliding 5-tap sums, 4 outputs per task ------
    // output col c maps to staged col c+2: s(c) = sum cs[c+2 .. c+6]
    const float inv = 1.0f / 25.0f;
    for (int t = threadIdx.x; t < TH * (TW / 4); t += NT) {
        const int r = t >> 4;            // / 16
        const int c = (t & 15) * 4;      // output col, %4 == 0
        const float4 A  = *reinterpret_cast<const float4*>(&cs [r][c]);
        const float4 B  = *reinterpret_cast<const float4*>(&cs [r][c + 4]);
        const float4 C  = *reinterpret_cast<const float4*>(&cs [r][c + 8]);
        const float4 A2 = *reinterpret_cast<const float4*>(&cs2[r][c]);
        const float4 B2 = *reinterpret_cast<const float4*>(&cs2[r][c + 4]);
        const float4 C2 = *reinterpret_cast<const float4*>(&cs2[r][c + 8]);

        // window values cs[c+2 .. c+9] = {A.z,A.w,B.x,B.y,B.z,B.w,C.x,C.y}
        const float s0 = A.z + A.w + B.x + B.y + B.z;
        const float s1 = s0 - A.z + B.w;
        const float s2 = s1 - A.w + C.x;
        const float s3 = s2 - B.x + C.y;
        const float q0 = A2.z + A2.w + B2.x + B2.y + B2.z;
        const float q1 = q0 - A2.z + B2.w;
        const float q2 = q1 - A2.w + C2.x;
        const float q3 = q2 - B2.x + C2.y;

        float4 res;
        float m;
        m = s0 * inv; res.x = fmaf(-m, m, q0 * inv);
        m = s1 * inv; res.y = fmaf(-m, m, q1 * inv);
        m = s2 * inv; res.z = fmaf(-m, m, q2 * inv);
        m = s3 * inv; res.w = fmaf(-m, m, q3 * inv);

        *reinterpret_cast<float4*>(
            o + (size_t)(by * TH + r) * W + bx * TW + c) = res;
    }
}

extern "C" void kernel_launch(void* const* d_in, const int* in_sizes, int n_in,
                              void* d_out, int out_size, void* d_ws, size_t ws_size,
                              hipStream_t stream) {
    const float* image = (const float*)d_in[0];
    float* out = (float*)d_out;

    const int H = 1024, W = 1024;
    const int BC = out_size / (H * W);   // 48

    dim3 grid(W / TW, H / TH, BC);       // (16, 32, 48)
    dim3 block(NT);
    lvar5x5_kernel<<<grid, block, 0, stream>>>(image, out, H, W);
}

// Round 3
// 335.095 us; speedup vs baseline: 1.2664x; 1.2121x over previous
//
#include <hip/hip_runtime.h>

// Local variance over a 5x5 sliding window, reflect padding.
// Pure-register separable stencil: NO LDS, NO barriers.
//
// Thread tile: 4 (W) x 8 (H) outputs. Block: 64 threads across W (256 cols),
// 4 thread-rows of 8 (32 rows). Grid: (W/256, H/32, B*C).
//
// Per input row (12 rows = 8 + 4 halo): 3 aligned float4 loads give cols
// c0-4 .. c0+7; the needed window is c0-2 .. c0+5. Horizontal 5-sums of x
// and x^2 via sliding adds; vertical 5-window via a register ring buffer
// (fully unrolled -> pure registers).
//
// Reflect (jnp "reflect", no edge repeat): rows are wave-uniform index math.
// Columns: clamp the two halo loads to the row, then:
//   left edge  (c0==0):    x2 needs col -2 -> col 2 == clamped v0.z (auto);
//                          x3 needs col -1 -> col 1  => x3 = x5
//   right edge (c0==W-4):  x8 needs col W  -> col W-2 => x8 = x6;
//                          x9 needs col W+1 -> col W-3 == clamped v2.y (auto)

constexpr int NT = 256;

__global__ __launch_bounds__(NT, 4)
void lvar5x5_reg_kernel(const float* __restrict__ in, float* __restrict__ out,
                        int H, int W) {
    const int tx = threadIdx.x & 63;     // column group within block
    const int ty = threadIdx.x >> 6;     // thread-row (wave-uniform)
    const int c0 = blockIdx.x * 256 + tx * 4;   // first output col
    const int r0 = blockIdx.y * 32 + ty * 8;    // first output row
    const size_t plane = (size_t)H * W;
    const float* __restrict__ img = in + (size_t)blockIdx.z * plane;
    float* __restrict__ o = out + (size_t)blockIdx.z * plane;

    const bool cL = (c0 == 0);
    const bool cR = (c0 == W - 4);
    const int a0 = cL ? 0 : c0 - 4;      // clamped left halo load col
    const int a2 = cR ? c0 : c0 + 4;     // clamped right halo load col

    float rh[5][4];                      // ring: horizontal sums of x
    float rq[5][4];                      // ring: horizontal sums of x^2
    float sh0 = 0.f, sh1 = 0.f, sh2 = 0.f, sh3 = 0.f;  // vertical running sums
    float sq0 = 0.f, sq1 = 0.f, sq2 = 0.f, sq3 = 0.f;

    const float inv = 1.0f / 25.0f;

#pragma unroll
    for (int i = 0; i < 12; ++i) {
        int gy = r0 - 2 + i;
        gy = (gy < 0) ? -gy : ((gy >= H) ? (2 * H - 2 - gy) : gy);
        const float* __restrict__ row = img + (size_t)gy * W;

        const float4 v0 = *reinterpret_cast<const float4*>(row + a0);
        const float4 v1 = *reinterpret_cast<const float4*>(row + c0);
        const float4 v2 = *reinterpret_cast<const float4*>(row + a2);

        const float x2 = v0.z;                 // col c0-2 (auto-correct at left edge)
        float       x3 = v0.w;                 // col c0-1
        const float x4 = v1.x, x5 = v1.y, x6 = v1.z, x7 = v1.w;
        float       x8 = v2.x;                 // col c0+4
        const float x9 = v2.y;                 // col c0+5 (auto-correct at right edge)
        if (cL) x3 = x5;                       // reflect col -1 -> col 1
        if (cR) x8 = x6;                       // reflect col W  -> col W-2

        // horizontal sliding 5-sums
        const float h0 = x2 + x3 + x4 + x5 + x6;
        const float h1 = h0 - x2 + x7;
        const float h2 = h1 - x3 + x8;
        const float h3 = h2 - x4 + x9;

        const float y2 = x2 * x2, y3 = x3 * x3, y4 = x4 * x4, y5 = x5 * x5;
        const float y6 = x6 * x6, y7 = x7 * x7, y8 = x8 * x8, y9 = x9 * x9;
        const float q0 = y2 + y3 + y4 + y5 + y6;
        const float q1 = q0 - y2 + y7;
        const float q2 = q1 - y3 + y8;
        const float q3 = q2 - y4 + y9;

        const int s = i % 5;                   // constant after unroll
        if (i >= 5) {
            sh0 -= rh[s][0]; sh1 -= rh[s][1]; sh2 -= rh[s][2]; sh3 -= rh[s][3];
            sq0 -= rq[s][0]; sq1 -= rq[s][1]; sq2 -= rq[s][2]; sq3 -= rq[s][3];
        }
        rh[s][0] = h0; rh[s][1] = h1; rh[s][2] = h2; rh[s][3] = h3;
        rq[s][0] = q0; rq[s][1] = q1; rq[s][2] = q2; rq[s][3] = q3;
        sh0 += h0; sh1 += h1; sh2 += h2; sh3 += h3;
        sq0 += q0; sq1 += q1; sq2 += q2; sq3 += q3;

        if (i >= 4) {
            float4 res;
            float m;
            m = sh0 * inv; res.x = fmaf(-m, m, sq0 * inv);
            m = sh1 * inv; res.y = fmaf(-m, m, sq1 * inv);
            m = sh2 * inv; res.z = fmaf(-m, m, sq2 * inv);
            m = sh3 * inv; res.w = fmaf(-m, m, sq3 * inv);
            *reinterpret_cast<float4*>(
                o + (size_t)(r0 + i - 4) * W + c0) = res;
        }
    }
}

extern "C" void kernel_launch(void* const* d_in, const int* in_sizes, int n_in,
                              void* d_out, int out_size, void* d_ws, size_t ws_size,
                              hipStream_t stream) {
    const float* image = (const float*)d_in[0];
    float* out = (float*)d_out;

    const int H = 1024, W = 1024;
    const int BC = out_size / (H * W);     // 48

    dim3 grid(W / 256, H / 32, BC);        // (4, 32, 48) = 6144 blocks
    dim3 block(NT);
    lvar5x5_reg_kernel<<<grid, block, 0, stream>>>(image, out, H, W);
}